// Round 4
// baseline (360.712 us; speedup 1.0000x reference)
//
#include <hip/hip_runtime.h>
#include <hip/hip_bf16.h>
#include <math.h>

#define B_ 4
#define T_ 4096
#define D_ 1024
#define E_ 8
#define K_ 2
#define C_ 1537   // int(T*K/E*1.5)+1

typedef short bf16x8 __attribute__((ext_vector_type(8)));
typedef float f32x4 __attribute__((ext_vector_type(4)));

__device__ __forceinline__ unsigned short f2bf(float f) {
    union { float f; unsigned int u; } c; c.f = f;
    unsigned int u = c.u;
    return (unsigned short)((u + 0x7fffu + ((u >> 16) & 1u)) >> 16);
}
__device__ __forceinline__ float bf2f(unsigned short u) {
    union { unsigned int i; float f; } c; c.i = ((unsigned int)u) << 16;
    return c.f;
}
__device__ __forceinline__ void ldsdma16(const void* g, void* l) {
    __builtin_amdgcn_global_load_lds((const __attribute__((address_space(1))) void*)g,
                                     (__attribute__((address_space(3))) void*)l, 16, 0, 0);
}

// ---------------------------------------------------------------------------
// Fat prep kernel: blocks 0..1023 = router (fp64 logits, top-2 softmax,
// fused x->bf16); blocks 1024..3071 = We transpose+convert.
// Block 0 also zero-inits the queue control words (consumed by later kernels).
// ---------------------------------------------------------------------------
__global__ __launch_bounds__(256) void prep_kernel(
    const float* __restrict__ x, const float* __restrict__ Wr,
    const float* __restrict__ We,
    unsigned short* __restrict__ xbf, unsigned short* __restrict__ wtbf,
    int* __restrict__ top_e, float* __restrict__ wbuf, int* __restrict__ qctl) {
    __shared__ char smem[32768];
    int tid = threadIdx.x;
    if (blockIdx.x < 1024) {
        // ---------------- router ----------------
        if (blockIdx.x == 0 && tid == 0) { qctl[0] = 0; qctl[1] = 0; }
        float* wr_s = (float*)smem;
        const float4* wr4 = (const float4*)Wr;
        float4* wrs4 = (float4*)wr_s;
        #pragma unroll
        for (int i = 0; i < 8; i++) wrs4[tid + i * 256] = wr4[tid + i * 256];
        __syncthreads();

        int wave = tid >> 6, lane = tid & 63;
        int h5 = (lane >> 5) & 1, h4 = (lane >> 4) & 1, h3 = (lane >> 3) & 1;

        for (int tt = 0; tt < 4; tt++) {
            int token = blockIdx.x * 16 + wave * 4 + tt;
            const float4* xr = (const float4*)(x + (size_t)token * D_) + lane * 4;
            float xs[16];
            #pragma unroll
            for (int i = 0; i < 4; i++) {
                float4 v = xr[i];
                xs[i * 4 + 0] = v.x; xs[i * 4 + 1] = v.y;
                xs[i * 4 + 2] = v.z; xs[i * 4 + 3] = v.w;
            }
            unsigned short xb[16];
            #pragma unroll
            for (int i = 0; i < 16; i++) xb[i] = f2bf(xs[i]);
            uint4* dst = (uint4*)(xbf + (size_t)token * D_ + lane * 16);
            dst[0] = ((uint4*)xb)[0];
            dst[1] = ((uint4*)xb)[1];

            double acc[E_];
            #pragma unroll
            for (int e = 0; e < E_; e++) {
                const float* wp = wr_s + e * D_ + lane * 16;
                double a = 0.0;
                #pragma unroll
                for (int i = 0; i < 16; i++) a += (double)xs[i] * (double)wp[i];
                acc[e] = a;
            }
            double r4[4];
            #pragma unroll
            for (int i = 0; i < 4; i++) {
                double send = h5 ? acc[i] : acc[4 + i];
                double keep = h5 ? acc[4 + i] : acc[i];
                r4[i] = keep + __shfl_xor(send, 32, 64);
            }
            double r2[2];
            #pragma unroll
            for (int i = 0; i < 2; i++) {
                double send = h4 ? r4[i] : r4[2 + i];
                double keep = h4 ? r4[2 + i] : r4[i];
                r2[i] = keep + __shfl_xor(send, 16, 64);
            }
            double r1;
            {
                double send = h3 ? r2[0] : r2[1];
                double keep = h3 ? r2[1] : r2[0];
                r1 = keep + __shfl_xor(send, 8, 64);
            }
            r1 += __shfl_xor(r1, 4, 64);
            r1 += __shfl_xor(r1, 2, 64);
            r1 += __shfl_xor(r1, 1, 64);
            double le[E_];
            #pragma unroll
            for (int e = 0; e < E_; e++) le[e] = __shfl(r1, e << 3, 64);

            if (lane == 0) {
                int e0 = 0; double v0 = le[0];
                #pragma unroll
                for (int e = 1; e < E_; e++) if (le[e] > v0) { v0 = le[e]; e0 = e; }
                int e1 = -1; double v1 = -1.0e300;
                #pragma unroll
                for (int e = 0; e < E_; e++) if (e != e0 && le[e] > v1) { v1 = le[e]; e1 = e; }
                double ex = exp(v1 - v0);
                top_e[token * 2 + 0] = e0;
                top_e[token * 2 + 1] = e1;
                wbuf[token * 2 + 0] = (float)(1.0 / (1.0 + ex));
                wbuf[token * 2 + 1] = (float)(ex / (1.0 + ex));
            }
        }
    } else {
        // ---------------- We[e][d][f] -> We_t[e][f][d] bf16 ----------------
        unsigned short (*tile)[65] = (unsigned short(*)[65])smem;
        int bid = blockIdx.x - 1024;
        int e = bid >> 8;
        int t = bid & 255;
        int d0 = (t >> 4) * 64, f0 = (t & 15) * 64;
        const float* src = We + ((size_t)e * D_ + d0) * D_ + f0;
        #pragma unroll
        for (int i = 0; i < 16; i++) {
            int idx = tid + i * 256;
            int r = idx >> 6, c = idx & 63;
            tile[r][c] = f2bf(src[(size_t)r * D_ + c]);
        }
        __syncthreads();
        unsigned short* dstp = wtbf + ((size_t)e * D_ + f0) * D_ + d0;
        #pragma unroll
        for (int i = 0; i < 16; i++) {
            int idx = tid + i * 256;
            int r = idx >> 6, c = idx & 63;
            dstp[(size_t)r * D_ + c] = tile[c][r];
        }
    }
}

// ---------------------------------------------------------------------------
// Exact (t,k)-order position scan per batch; parallel wave scans.
// Last-finishing block builds the gemm work-item prefix table (device-scope
// atomic last-done pattern) -> qctl[2]=total, qctl[8..40]=pref[0..32].
// ---------------------------------------------------------------------------
__global__ __launch_bounds__(256) void scan_kernel(const int* __restrict__ top_e,
                                                   int* __restrict__ list,
                                                   int* __restrict__ count,
                                                   unsigned char* __restrict__ keep8,
                                                   int* __restrict__ qctl) {
    int b = blockIdx.x, tid = threadIdx.x;
    const int per = 32;
    __shared__ int cnt[256][9];
    int local[E_];
    #pragma unroll
    for (int e = 0; e < E_; e++) local[e] = 0;
    const int* te = top_e + (size_t)b * 8192 + tid * per;
    int evals[32];
    for (int i = 0; i < per; i++) { evals[i] = te[i]; local[evals[i]]++; }
    #pragma unroll
    for (int e = 0; e < E_; e++) cnt[tid][e] = local[e];
    __syncthreads();

    int wave = tid >> 6, lane = tid & 63;
    #pragma unroll
    for (int ee = 0; ee < 2; ee++) {
        int e = wave * 2 + ee;
        int s0 = cnt[lane * 4 + 0][e], s1 = cnt[lane * 4 + 1][e];
        int s2 = cnt[lane * 4 + 2][e], s3 = cnt[lane * 4 + 3][e];
        int tot = s0 + s1 + s2 + s3;
        int s = tot;
        #pragma unroll
        for (int off = 1; off < 64; off <<= 1) {
            int t2 = __shfl_up(s, off, 64);
            if (lane >= off) s += t2;
        }
        int base = s - tot;
        cnt[lane * 4 + 0][e] = base;
        cnt[lane * 4 + 1][e] = base + s0;
        cnt[lane * 4 + 2][e] = base + s0 + s1;
        cnt[lane * 4 + 3][e] = base + s0 + s1 + s2;
        if (lane == 63) count[b * E_ + e] = min(s, C_);
    }
    __syncthreads();

    int base[E_];
    #pragma unroll
    for (int e = 0; e < E_; e++) base[e] = cnt[tid][e];
    int* lst = list + (size_t)b * E_ * C_;
    unsigned char* kp = keep8 + (size_t)b * 8192;
    for (int i = 0; i < per; i++) {
        int ev = evals[i];
        int p = base[ev]++;
        int slot = tid * per + i;
        kp[slot] = (p < C_) ? 1 : 0;
        if (p < C_) lst[ev * C_ + p] = slot;
    }
    __syncthreads();
    if (tid == 0) {
        __threadfence();
        if (atomicAdd(&qctl[1], 1) == B_ - 1) {
            __threadfence();
            int run = 0;
            qctl[8] = 0;
            for (int pe = 0; pe < B_ * E_; pe++) {
                int c = count[pe];
                run += ((c + 127) >> 7) * 8;   // nrb * 8 col-blocks
                qctl[9 + pe] = run;
            }
            qctl[2] = run;
            __threadfence();
        }
    }
}

// ---------------------------------------------------------------------------
// Persistent grouped expert GEMM: 1024 blocks pop (pe,rb,cb) items from a
// device queue (cb fastest -> L2 locality). m97 structure per item:
// 128x128 tile, BK=64, single-buffer LDS, both operands via global_load_lds.
// ---------------------------------------------------------------------------
__global__ __launch_bounds__(256, 4) void gemm_kernel(
    const unsigned short* __restrict__ xbf, const unsigned short* __restrict__ wtbf,
    const int* __restrict__ list, const int* __restrict__ count,
    int* __restrict__ qctl, unsigned short* __restrict__ gbuf) {
    __shared__ unsigned short As[128 * 64];  // 16 KB
    __shared__ unsigned short Bs[128 * 64];  // 16 KB
    __shared__ unsigned int rowByte[128];
    __shared__ int slotArr[128];
    __shared__ int prefS[33];
    __shared__ int countS[32];
    __shared__ int itemS;

    int tid = threadIdx.x;
    if (tid < 33) prefS[tid] = qctl[8 + tid];
    if (tid >= 64 && tid < 96) countS[tid - 64] = count[tid - 64];
    int total = qctl[2];

    int wave = tid >> 6, lane = tid & 63;
    int quad = lane >> 4, mrow = lane & 15;
    int wm = wave >> 1, wn = wave & 1;
    const char* xbase = (const char*)xbf;
    const char* wtbase = (const char*)wtbf;

    while (true) {
        if (tid == 0) itemS = atomicAdd(&qctl[0], 1);
        __syncthreads();
        int item = itemS;
        if (item >= total) break;

        // decode item -> (pe, rb, cb), cb fastest
        int pe = 0;
        #pragma unroll
        for (int p = 1; p < 32; p++) pe += (item >= prefS[p]) ? 1 : 0;
        int local = item - prefS[pe];
        int rb = local >> 3;
        int cb = local & 7;
        int b = pe >> 3, e = pe & 7;
        int cnt = countS[pe];
        int row0 = rb * 128;
        int rows = min(128, cnt - row0);

        if (tid < 128) {
            int slot = list[pe * C_ + row0 + min(tid, rows - 1)];
            slotArr[tid] = (tid < rows) ? slot : -1;
            rowByte[tid] = (unsigned)(((b << 12) + (slot >> 1)) << 11);
        }
        __syncthreads();

        unsigned aAddr[4], bAddr[4];
        #pragma unroll
        for (int i = 0; i < 4; i++) {
            int g = wave * 4 + i;
            int row = (g & 7) * 16 + mrow;
            unsigned kcb = (unsigned)(((g >> 3) * 4 + quad) * 16);
            aAddr[i] = rowByte[row] + kcb;
            int nrow = cb * 128 + row;
            bAddr[i] = (unsigned)((((e << 10) + nrow) << 11) + kcb);
        }

        f32x4 acc[4][4];
        #pragma unroll
        for (int i = 0; i < 4; i++)
            #pragma unroll
            for (int j = 0; j < 4; j++) acc[i][j] = (f32x4){0.f, 0.f, 0.f, 0.f};

        for (int kk = 0; kk < 16; kk++) {
            unsigned ko = (unsigned)kk * 128u;
            __syncthreads();
            #pragma unroll
            for (int i = 0; i < 4; i++) {
                int g = wave * 4 + i;
                ldsdma16(xbase + aAddr[i] + ko, &As[g * 512]);
                ldsdma16(wtbase + bAddr[i] + ko, &Bs[g * 512]);
            }
            __syncthreads();
            #pragma unroll
            for (int ks = 0; ks < 2; ks++) {
                bf16x8 af[4], bfv[4];
                #pragma unroll
                for (int it = 0; it < 4; it++)
                    af[it] = *(const bf16x8*)(As + (ks * 8 + wm * 4 + it) * 512 + lane * 8);
                #pragma unroll
                for (int jt = 0; jt < 4; jt++)
                    bfv[jt] = *(const bf16x8*)(Bs + (ks * 8 + wn * 4 + jt) * 512 + lane * 8);
                #pragma unroll
                for (int it = 0; it < 4; it++)
                    #pragma unroll
                    for (int jt = 0; jt < 4; jt++)
                        acc[it][jt] = __builtin_amdgcn_mfma_f32_16x16x32_bf16(
                            af[it], bfv[jt], acc[it][jt], 0, 0, 0);
            }
        }

        // epilogue: C/D col = mrow (n), row = quad*4 + r (m)
        int colbase = cb * 128 + wn * 64 + mrow;
        #pragma unroll
        for (int it = 0; it < 4; it++) {
            int mbase = wm * 64 + it * 16 + quad * 4;
            #pragma unroll
            for (int r = 0; r < 4; r++) {
                int slot = slotArr[mbase + r];
                if (slot >= 0) {
                    unsigned short* grow = gbuf + ((size_t)((b << 13) + slot) << 10);
                    #pragma unroll
                    for (int jt = 0; jt < 4; jt++)
                        grow[colbase + jt * 16] = f2bf(acc[it][jt][r]);
                }
            }
        }
        // loop-top __syncthreads separates epilogue reads from next item's writes
    }
}

// ---------------------------------------------------------------------------
// Combine (grid-stride): out[t,:] = w0*keep0*g[slot0,:] + w1*keep1*g[slot1,:]
// ---------------------------------------------------------------------------
__global__ __launch_bounds__(256) void combine_kernel(
    const unsigned short* __restrict__ gbuf, const float* __restrict__ wbuf,
    const unsigned char* __restrict__ keep8, float* __restrict__ out) {
    const int NV = B_ * T_ * (D_ / 4);     // total float4 elems
    int stride = gridDim.x * blockDim.x;
    for (int i = blockIdx.x * blockDim.x + threadIdx.x; i < NV; i += stride) {
        int t = i >> 8;            // token
        int ch = i & 255;          // float4 chunk within row
        int b = t >> 12;
        int kb = (b << 13) + ((t & 4095) << 1);
        float w0 = wbuf[t * 2 + 0] * (float)keep8[kb + 0];
        float w1 = wbuf[t * 2 + 1] * (float)keep8[kb + 1];
        ushort4 a = ((const ushort4*)(gbuf + ((size_t)kb << 10)))[ch];
        ushort4 c = ((const ushort4*)(gbuf + (((size_t)kb + 1) << 10)))[ch];
        float4 o;
        o.x = w0 * bf2f(a.x) + w1 * bf2f(c.x);
        o.y = w0 * bf2f(a.y) + w1 * bf2f(c.y);
        o.z = w0 * bf2f(a.z) + w1 * bf2f(c.z);
        o.w = w0 * bf2f(a.w) + w1 * bf2f(c.w);
        ((float4*)(out + (size_t)t * D_))[ch] = o;
    }
}

// ---------------------------------------------------------------------------
extern "C" void kernel_launch(void* const* d_in, const int* in_sizes, int n_in,
                              void* d_out, int out_size, void* d_ws, size_t ws_size,
                              hipStream_t stream) {
    const float* x  = (const float*)d_in[0];
    const float* Wr = (const float*)d_in[1];
    const float* We = (const float*)d_in[2];
    float* out = (float*)d_out;
    char* ws = (char*)d_ws;

    unsigned short* xbf  = (unsigned short*)(ws);              //  33,554,432
    unsigned short* wtbf = (unsigned short*)(ws + 33554432);   //  16,777,216
    unsigned short* gbuf = (unsigned short*)(ws + 50331648);   //  67,108,864
    int*   top_e = (int*)  (ws + 117440512);                   //     131,072
    float* wbuf  = (float*)(ws + 117571584);                   //     131,072
    int*   list  = (int*)  (ws + 117702656);                   //     196,736
    int*   count = (int*)  (ws + 117899392);                   //         256
    unsigned char* keep8 = (unsigned char*)(ws + 117899648);   //      32,768
    int*   qctl  = (int*)  (ws + 117932416);                   //         256

    prep_kernel<<<dim3(1024 + 2048), dim3(256), 0, stream>>>(x, Wr, We, xbf, wtbf,
                                                             top_e, wbuf, qctl);
    scan_kernel<<<dim3(B_), dim3(256), 0, stream>>>(top_e, list, count, keep8, qctl);
    gemm_kernel<<<dim3(1024), dim3(256), 0, stream>>>(xbf, wtbf, list, count, qctl, gbuf);
    combine_kernel<<<dim3(1024), dim3(256), 0, stream>>>(gbuf, wbuf, keep8, out);
}